// Round 7
// baseline (259.525 us; speedup 1.0000x reference)
//
#include <hip/hip_runtime.h>
#include <math.h>

typedef unsigned short u16;
typedef unsigned int u32;
typedef __attribute__((ext_vector_type(8))) short short8;   // 8 bf16 (4 VGPRs) MFMA A/B frag
typedef __attribute__((ext_vector_type(4))) float f32x4;    // MFMA C/D frag

#define EPS 1e-8f

// ---------- helpers ----------
__device__ inline float bf2f(u16 u) {
    union { u32 i; float f; } v; v.i = ((u32)u) << 16; return v.f;
}
__device__ inline u16 f2bf(float f) {  // RNE
    union { float f; u32 u; } v; v.f = f;
    u32 r = v.u + 0x7fffu + ((v.u >> 16) & 1u);
    return (u16)(r >> 16);
}
__device__ inline u32 pack2(float a, float b) {
    return (u32)f2bf(a) | ((u32)f2bf(b) << 16);
}
__device__ inline float wave_sum(float v) {
    for (int off = 32; off; off >>= 1) v += __shfl_xor(v, off, 64);
    return v;
}

// ---------- K1: prep = vis normalize (fp32+bf16) + raw bf16 + Wq/Wv/Wo cvt ----------
__global__ __launch_bounds__(256) void prep(const float* __restrict__ vis,
                                            const float* __restrict__ ipw,
                                            const float* __restrict__ opw,
                                            float* __restrict__ vis_n,
                                            u16* __restrict__ vis_nb,
                                            u16* __restrict__ vis_b,
                                            u16* __restrict__ wqb,
                                            u16* __restrict__ wvb,
                                            u16* __restrict__ wob,
                                            float* __restrict__ loss0)
{
    int bid = blockIdx.x;
    if (bid >= 128) {
        int i = ((bid - 128) * 256 + threadIdx.x) * 4;   // 786432 elems
        const float* src; u16* dst; int j;
        if (i < 262144)      { j = i;          src = ipw + j;          dst = wqb + j; }
        else if (i < 524288) { j = i - 262144; src = ipw + 524288 + j; dst = wvb + j; }
        else                 { j = i - 524288; src = opw + j;          dst = wob + j; }
        float4 v = *(const float4*)src;
        uint2 pk; pk.x = pack2(v.x, v.y); pk.y = pack2(v.z, v.w);
        *(uint2*)dst = pk;
        return;
    }
    if (bid == 0 && threadIdx.x == 0) loss0[0] = 0.0f;
    int wave = threadIdx.x >> 6, lane = threadIdx.x & 63;
    int b = bid * 4 + wave;                      // B = 512
    const float* row = vis + b * 512 + lane * 8;
    float4 x0 = *(const float4*)row;
    float4 x1 = *(const float4*)(row + 4);
    uint4 rk;
    rk.x = pack2(x0.x, x0.y); rk.y = pack2(x0.z, x0.w);
    rk.z = pack2(x1.x, x1.y); rk.w = pack2(x1.z, x1.w);
    *(uint4*)(vis_b + b*512 + lane*8) = rk;
    float ss = x0.x*x0.x + x0.y*x0.y + x0.z*x0.z + x0.w*x0.w
             + x1.x*x1.x + x1.y*x1.y + x1.z*x1.z + x1.w*x1.w;
    ss = wave_sum(ss);
    float inv = 1.0f / fmaxf(sqrtf(ss), EPS);
    float4 y0, y1;
    y0.x = x0.x*inv; y0.y = x0.y*inv; y0.z = x0.z*inv; y0.w = x0.w*inv;
    y1.x = x1.x*inv; y1.y = x1.y*inv; y1.z = x1.z*inv; y1.w = x1.w*inv;
    *(float4*)(vis_n + b*512 + lane*8)     = y0;
    *(float4*)(vis_n + b*512 + lane*8 + 4) = y1;
    uint4 pk;
    pk.x = pack2(y0.x, y0.y); pk.y = pack2(y0.z, y0.w);
    pk.z = pack2(y1.x, y1.y); pk.w = pack2(y1.z, y1.w);
    *(uint4*)(vis_nb + b*512 + lane*8) = pk;
}

// ---------- gemm64: C(MxN) = A(Mx512,bf16) @ B(Nx512,bf16)^T [+bias], fp32 out ----------
__global__ __launch_bounds__(256) void gemm64(const u16* __restrict__ A, int lda,
                                              const u16* __restrict__ B,
                                              const float* __restrict__ bias,
                                              float* __restrict__ Cf, int ldc)
{
    __shared__ __align__(16) u16 As[64 * 64];
    __shared__ __align__(16) u16 Bs[64 * 64];
    const int t = threadIdx.x, lane = t & 63, w = t >> 6;
    const int m0 = blockIdx.x * 64, n0 = blockIdx.y * 64;
    const int wm = (w >> 1) * 32, wn = (w & 1) * 32;
    const int l16 = lane & 15, quad = lane >> 4;
    const int srow = t >> 3, scol = (t & 7) * 8;

    f32x4 acc[2][2];
    for (int i = 0; i < 2; i++)
        for (int j = 0; j < 2; j++)
            for (int e = 0; e < 4; e++) acc[i][j][e] = 0.f;

    for (int ko = 0; ko < 512; ko += 64) {
        __syncthreads();
        #pragma unroll
        for (int i = 0; i < 2; i++) {
            int row = i * 32 + srow;
            *(uint4*)&As[row * 64 + scol] = *(const uint4*)&A[(size_t)(m0 + row) * lda + ko + scol];
            *(uint4*)&Bs[row * 64 + scol] = *(const uint4*)&B[(size_t)(n0 + row) * 512 + ko + scol];
        }
        __syncthreads();
        #pragma unroll
        for (int ks = 0; ks < 2; ks++) {
            short8 af[2], bfr[2];
            #pragma unroll
            for (int i = 0; i < 2; i++)
                af[i] = *(const short8*)&As[(wm + i * 16 + l16) * 64 + ks * 32 + quad * 8];
            #pragma unroll
            for (int j = 0; j < 2; j++)
                bfr[j] = *(const short8*)&Bs[(wn + j * 16 + l16) * 64 + ks * 32 + quad * 8];
            #pragma unroll
            for (int i = 0; i < 2; i++)
                #pragma unroll
                for (int j = 0; j < 2; j++)
                    acc[i][j] = __builtin_amdgcn_mfma_f32_16x16x32_bf16(af[i], bfr[j], acc[i][j], 0, 0, 0);
        }
    }
    for (int i = 0; i < 2; i++) {
        int row = m0 + wm + i * 16 + quad * 4;
        for (int j = 0; j < 2; j++) {
            int col = n0 + wn + j * 16 + l16;
            float bv = bias ? bias[col] : 0.f;
            for (int r = 0; r < 4; r++)
                Cf[(size_t)(row + r) * ldc + col] = acc[i][j][r] + bv;
        }
    }
}

// ---------- gemm_head: ctx_h(512x64) = u_h(512x512) @ Wv_h(64x512)^T + bv_h, bf16 out ----------
__global__ __launch_bounds__(256) void gemm_head(const u16* __restrict__ u_allb,
                                                 const u16* __restrict__ wvb,
                                                 const float* __restrict__ bv,
                                                 u16* __restrict__ ctxb)
{
    const int h = blockIdx.y;
    const u16* A = u_allb + h * 512;                 // lda 4096
    const u16* B = wvb + (size_t)h * 64 * 512;       // 64 rows, ldb 512
    __shared__ __align__(16) u16 As[64 * 64];
    __shared__ __align__(16) u16 Bs[64 * 64];
    const int t = threadIdx.x, lane = t & 63, w = t >> 6;
    const int m0 = blockIdx.x * 64;
    const int wm = (w >> 1) * 32, wn = (w & 1) * 32;
    const int l16 = lane & 15, quad = lane >> 4;
    const int srow = t >> 3, scol = (t & 7) * 8;

    f32x4 acc[2][2];
    for (int i = 0; i < 2; i++)
        for (int j = 0; j < 2; j++)
            for (int e = 0; e < 4; e++) acc[i][j][e] = 0.f;

    for (int ko = 0; ko < 512; ko += 64) {
        __syncthreads();
        #pragma unroll
        for (int i = 0; i < 2; i++) {
            int row = i * 32 + srow;
            *(uint4*)&As[row * 64 + scol] = *(const uint4*)&A[(size_t)(m0 + row) * 4096 + ko + scol];
            *(uint4*)&Bs[row * 64 + scol] = *(const uint4*)&B[(size_t)row * 512 + ko + scol];
        }
        __syncthreads();
        #pragma unroll
        for (int ks = 0; ks < 2; ks++) {
            short8 af[2], bfr[2];
            #pragma unroll
            for (int i = 0; i < 2; i++)
                af[i] = *(const short8*)&As[(wm + i * 16 + l16) * 64 + ks * 32 + quad * 8];
            #pragma unroll
            for (int j = 0; j < 2; j++)
                bfr[j] = *(const short8*)&Bs[(wn + j * 16 + l16) * 64 + ks * 32 + quad * 8];
            #pragma unroll
            for (int i = 0; i < 2; i++)
                #pragma unroll
                for (int j = 0; j < 2; j++)
                    acc[i][j] = __builtin_amdgcn_mfma_f32_16x16x32_bf16(af[i], bfr[j], acc[i][j], 0, 0, 0);
        }
    }
    for (int i = 0; i < 2; i++) {
        int row = m0 + wm + i * 16 + quad * 4;
        for (int j = 0; j < 2; j++) {
            int col = wn + j * 16 + l16;
            float bb = bv[h * 64 + col];
            for (int r = 0; r < 4; r++)
                ctxb[(size_t)(row + r) * 512 + h * 64 + col] = f2bf(acc[i][j][r] + bb);
        }
    }
}

// ---------- qk_proj: qk_all[b,h,j] = sum_d q[b,h*64+d] * wk[h*64+d, j]  (fp32) ----------
__global__ __launch_bounds__(256) void qk_proj(const float* __restrict__ q,
                                               const float* __restrict__ wk,
                                               float* __restrict__ qk_all)
{
    int bg = blockIdx.x, h = blockIdx.y;
    int t = threadIdx.x;
    int j = blockIdx.z * 256 + t;
    __shared__ float q8[8][64];
    {
        int r = t >> 5;
        int d0 = (t & 31) * 2;
        const float* qp = q + (bg * 8 + r) * 512 + h * 64 + d0;
        q8[r][d0] = qp[0]; q8[r][d0 + 1] = qp[1];
    }
    __syncthreads();
    float acc[8] = {0, 0, 0, 0, 0, 0, 0, 0};
    const float* wrow = wk + (size_t)(h * 64) * 512 + j;
    #pragma unroll 4
    for (int d = 0; d < 64; d++) {
        float ww = wrow[(size_t)d * 512];
        #pragma unroll
        for (int r = 0; r < 8; r++) acc[r] += q8[r][d] * ww;
    }
    #pragma unroll
    for (int r = 0; r < 8; r++)
        qk_all[((size_t)(bg * 8 + r) * 8 + h) * 512 + j] = acc[r];
}

// ---------- score_pass: per (b, 48-row half): sims (fp32) + scores = X@qk^T (MFMA) ----------
__global__ __launch_bounds__(256) void score_pass(const float* __restrict__ tf,
                                                  const float* __restrict__ vis_n,
                                                  const float* __restrict__ qk_all,
                                                  float* __restrict__ scores,
                                                  float* __restrict__ sims_g)
{
    __shared__ __align__(16) u16 Xs[48 * 520];     // 49920 B
    __shared__ __align__(16) u16 Bs16[16 * 520];   // 16640 B (rows 8..15 garbage, cols unused)
    const int bid = blockIdx.x;
    const int b = bid >> 1, half = bid & 1;
    const int t = threadIdx.x, w = t >> 6, lane = t & 63;
    const int l16 = lane & 15, quad = lane >> 4;

    // stage qk_b rows 0..7 as bf16
    #pragma unroll
    for (int i = 0; i < 2; i++) {
        int idx = t + 256 * i;                   // 0..511
        int row = idx >> 6, col = (idx & 63) * 8;
        const float4* q4 = (const float4*)(qk_all + ((size_t)b * 8 + row) * 512 + col);
        float4 a = q4[0], c = q4[1];
        uint4 pk;
        pk.x = pack2(a.x, a.y); pk.y = pack2(a.z, a.w);
        pk.z = pack2(c.x, c.y); pk.w = pack2(c.z, c.w);
        *(uint4*)&Bs16[row * 520 + col] = pk;
    }
    const float4* v4 = (const float4*)(vis_n + b * 512 + lane * 8);
    float4 va = v4[0], vb = v4[1];

    // stage Xs (bf16) + ss/dot shuffles -> sims (fp32, same math as round-5)
    #pragma unroll 2
    for (int i = 0; i < 6; i++) {
        int mA = w * 12 + i, mB = mA + 6;        // 12 rows per wave
        int gA = b * 96 + half * 48 + mA;
        int gB = b * 96 + half * 48 + mB;
        const float4* x4a = (const float4*)(tf + (size_t)gA * 512 + lane * 8);
        const float4* x4b = (const float4*)(tf + (size_t)gB * 512 + lane * 8);
        float4 a0 = x4a[0], c0 = x4a[1];
        float4 a1 = x4b[0], c1 = x4b[1];
        float ss0 = a0.x*a0.x + a0.y*a0.y + a0.z*a0.z + a0.w*a0.w
                  + c0.x*c0.x + c0.y*c0.y + c0.z*c0.z + c0.w*c0.w;
        float dt0 = a0.x*va.x + a0.y*va.y + a0.z*va.z + a0.w*va.w
                  + c0.x*vb.x + c0.y*vb.y + c0.z*vb.z + c0.w*vb.w;
        float ss1 = a1.x*a1.x + a1.y*a1.y + a1.z*a1.z + a1.w*a1.w
                  + c1.x*c1.x + c1.y*c1.y + c1.z*c1.z + c1.w*c1.w;
        float dt1 = a1.x*va.x + a1.y*va.y + a1.z*va.z + a1.w*va.w
                  + c1.x*vb.x + c1.y*vb.y + c1.z*vb.z + c1.w*vb.w;
        #pragma unroll
        for (int off = 32; off; off >>= 1) {
            ss0 += __shfl_xor(ss0, off, 64);
            dt0 += __shfl_xor(dt0, off, 64);
            ss1 += __shfl_xor(ss1, off, 64);
            dt1 += __shfl_xor(dt1, off, 64);
        }
        if (lane == 0) {
            sims_g[gA] = dt0 / fmaxf(sqrtf(ss0), EPS);
            sims_g[gB] = dt1 / fmaxf(sqrtf(ss1), EPS);
        }
        uint4 pk0, pk1;
        pk0.x = pack2(a0.x, a0.y); pk0.y = pack2(a0.z, a0.w);
        pk0.z = pack2(c0.x, c0.y); pk0.w = pack2(c0.z, c0.w);
        pk1.x = pack2(a1.x, a1.y); pk1.y = pack2(a1.z, a1.w);
        pk1.z = pack2(c1.x, c1.y); pk1.w = pack2(c1.z, c1.w);
        *(uint4*)&Xs[mA * 520 + lane * 8] = pk0;
        *(uint4*)&Xs[mB * 520 + lane * 8] = pk1;
    }
    __syncthreads();

    // scores: D[m][c] = X_m . qk_c, waves 0..2 take 16-row mtiles
    if (w < 3) {
        f32x4 acc;
        for (int e = 0; e < 4; e++) acc[e] = 0.f;
        #pragma unroll
        for (int ks = 0; ks < 16; ks++) {
            short8 a = *(const short8*)&Xs[(w * 16 + l16) * 520 + ks * 32 + quad * 8];
            short8 q = *(const short8*)&Bs16[l16 * 520 + ks * 32 + quad * 8];
            acc = __builtin_amdgcn_mfma_f32_16x16x32_bf16(a, q, acc, 0, 0, 0);
        }
        if (l16 < 8) {
            #pragma unroll
            for (int r = 0; r < 4; r++) {
                int m = half * 48 + w * 16 + quad * 4 + r;
                scores[((size_t)b * 96 + m) * 8 + l16] = acc[r] * 0.125f;
            }
        }
    }
}

// ---------- pv_cluster: softmax + cluster + u = P@X (streamed 32-row chunks) ----------
__global__ __launch_bounds__(256) void pv_cluster(const float* __restrict__ tf,
                                                  const float* __restrict__ scores,
                                                  const float* __restrict__ sims_g,
                                                  u16* __restrict__ u_allb,
                                                  float* __restrict__ out_cs)
{
    __shared__ __align__(16) u16 Xs[32 * 520];     // 33280 B
    __shared__ __align__(16) u16 Ps[16 * 104];     //  3328 B
    __shared__ float sm_[96], srt[96], linv[8];
    const int b = blockIdx.x;
    const int t = threadIdx.x, w = t >> 6, lane = t & 63;
    const int l16 = lane & 15, quad = lane >> 4;

    // softmax: wave w handles heads 2w, 2w+1 (unnormalized exp in Ps + linv)
    #pragma unroll
    for (int hh = 0; hh < 2; hh++) {
        int h = w * 2 + hh;
        float e0 = __expf(scores[((size_t)b * 96 + lane) * 8 + h]);
        float e1 = (lane < 32) ? __expf(scores[((size_t)b * 96 + 64 + lane) * 8 + h]) : 0.f;
        float l = wave_sum(e0 + e1);
        Ps[h * 104 + lane] = f2bf(e0);
        if (lane < 32) Ps[h * 104 + 64 + lane] = f2bf(e1);
        if (lane == 0) linv[h] = 1.0f / l;
    }
    if (t < 96) sm_[t] = sims_g[b * 96 + t];
    __syncthreads();
    if (t < 96) {
        float v = sm_[t]; int r = 0;
        for (int j = 0; j < 96; j++) {
            float u = sm_[j];
            r += (u > v) || (u == v && j < t);
        }
        srt[r] = v;
    }

    f32x4 acc[8];
    #pragma unroll
    for (int jj = 0; jj < 8; jj++)
        for (int e = 0; e < 4; e++) acc[jj][e] = 0.f;

    for (int c = 0; c < 3; c++) {
        // stage 32 rows of X_b (bf16); wave w rows w*8..w*8+7
        #pragma unroll
        for (int i = 0; i < 8; i++) {
            int rl = w * 8 + i;
            const float4* x4 = (const float4*)(tf + ((size_t)b * 96 + c * 32 + rl) * 512 + lane * 8);
            float4 a = x4[0], cc = x4[1];
            uint4 pk;
            pk.x = pack2(a.x, a.y); pk.y = pack2(a.z, a.w);
            pk.z = pack2(cc.x, cc.y); pk.w = pack2(cc.z, cc.w);
            *(uint4*)&Xs[rl * 520 + lane * 8] = pk;
        }
        __syncthreads();                          // Xs ready (and srt, on c==0)
        if (c == 0 && t < 3) {
            float mean = 0.f;
            #pragma unroll 8
            for (int i = 0; i < 32; i++) mean += srt[t * 32 + i];
            mean *= (1.0f / 32.0f);
            float var = 0.f;
            #pragma unroll 8
            for (int i = 0; i < 32; i++) { float d = srt[t * 32 + i] - mean; var += d * d; }
            var *= (1.0f / 31.0f);
            out_cs[b * 3 + t] = mean / (sqrtf(var) + 1e-6f);
        }
        short8 ap = *(const short8*)&Ps[l16 * 104 + c * 32 + quad * 8];
        #pragma unroll
        for (int jj = 0; jj < 8; jj++) {
            int n0 = (w * 8 + jj) * 16;
            short8 bx;
            #pragma unroll
            for (int j = 0; j < 8; j++)
                bx[j] = (short)Xs[(quad * 8 + j) * 520 + n0 + l16];
            acc[jj] = __builtin_amdgcn_mfma_f32_16x16x32_bf16(ap, bx, acc[jj], 0, 0, 0);
        }
        if (c < 2) __syncthreads();               // before restaging Xs
    }
    if (quad < 2) {
        #pragma unroll
        for (int jj = 0; jj < 8; jj++) {
            int n0 = (w * 8 + jj) * 16;
            #pragma unroll
            for (int r = 0; r < 4; r++) {
                int h = quad * 4 + r;
                u_allb[((size_t)b * 8 + h) * 512 + n0 + l16] = f2bf(acc[jj][r] * linv[h]);
            }
        }
    }
}

// ---------- negs_build: normalized negatives (bf16) + pos_sim ----------
__global__ __launch_bounds__(256) void negs_build(const float* __restrict__ corrected,
                                                  const float* __restrict__ tm,
                                                  const float* __restrict__ vis_n,
                                                  u16* __restrict__ negs_nb,
                                                  float* __restrict__ pos)
{
    int wave = threadIdx.x >> 6, lane = threadIdx.x & 63;
    int j = blockIdx.x * 4 + wave;
    const float* src = (j < 512) ? (corrected + j * 512) : (tm + j * 512);
    const float* row = src + lane * 8;
    float4 x0 = *(const float4*)row;
    float4 x1 = *(const float4*)(row + 4);
    float ss = x0.x*x0.x + x0.y*x0.y + x0.z*x0.z + x0.w*x0.w
             + x1.x*x1.x + x1.y*x1.y + x1.z*x1.z + x1.w*x1.w;
    float dt = 0.f;
    if (j < 512) {
        const float* vn = vis_n + j * 512 + lane * 8;
        float4 v0 = *(const float4*)vn;
        float4 v1 = *(const float4*)(vn + 4);
        dt = x0.x*v0.x + x0.y*v0.y + x0.z*v0.z + x0.w*v0.w
           + x1.x*v1.x + x1.y*v1.y + x1.z*v1.z + x1.w*v1.w;
    }
    ss = wave_sum(ss);
    dt = wave_sum(dt);
    float inv = 1.0f / fmaxf(sqrtf(ss), EPS);
    uint4 pk;
    pk.x = pack2(x0.x*inv, x0.y*inv); pk.y = pack2(x0.z*inv, x0.w*inv);
    pk.z = pack2(x1.x*inv, x1.y*inv); pk.w = pack2(x1.z*inv, x1.w*inv);
    *(uint4*)(negs_nb + (size_t)j * 512 + lane * 8) = pk;
    if (j < 512 && lane == 0) pos[j] = dt * inv;
}

// ---------- topk_loss: top-5 (1024 distinct, first 512 mult 2) + loss ----------
__global__ __launch_bounds__(256) void topk_loss(const float* __restrict__ ns,
                                                 const float* __restrict__ pos,
                                                 const float* __restrict__ tau_p_log,
                                                 const float* __restrict__ tau_n_log,
                                                 float* __restrict__ out_loss)
{
    int b = blockIdx.x, t = threadIdx.x;
    int w = t >> 6, lane = t & 63;
    __shared__ float cand_v[4];
    __shared__ int   cand_m[4];

    const float4 raw = *(const float4*)(ns + b * 1024 + t * 4);
    float lv[4] = {raw.x, raw.y, raw.z, raw.w};
    #pragma unroll
    for (int i = 1; i < 4; i++) {
        float key = lv[i];
        int j = i - 1;
        #pragma unroll
        for (int k = 0; k < 3; k++) {
            if (j >= 0 && lv[j] < key) { lv[j + 1] = lv[j]; j--; }
        }
        lv[j + 1] = key;
    }
    int lp = 0;

    float tn = expf(tau_n_log[0]);
    float inv_tn = 1.0f / tn;
    float nsum = 0.f;
    int collected = 0;

    for (int round = 0; round < 5 && collected < 5; round++) {
        float head = (lp < 4) ? lv[lp] : -1e30f;
        float mv = head; int ml = lane;
        #pragma unroll
        for (int off = 32; off; off >>= 1) {
            float ov = __shfl_xor(mv, off, 64);
            int   ol = __shfl_xor(ml, off, 64);
            if (ov > mv || (ov == mv && ol < ml)) { mv = ov; ml = ol; }
        }
        if (lane == 0) { cand_v[w] = mv; cand_m[w] = ml; }
        __syncthreads();
        float bv = cand_v[0]; int bw = 0;
        #pragma unroll
        for (int i = 1; i < 4; i++) {
            if (cand_v[i] > bv) { bv = cand_v[i]; bw = i; }
        }
        int bl = cand_m[bw];
        __syncthreads();
        if (w == bw && lane == bl) lp++;
        int wm = ((bw * 64 + bl) < 128) ? 2 : 1;
        int take = (wm < (5 - collected)) ? wm : (5 - collected);
        nsum += (float)take * __expf(bv * inv_tn);
        collected += take;
    }

    if (t == 0) {
        float tp = expf(tau_p_log[0]);
        float p = expf(pos[b] / tp);
        float term = logf(p / (p + nsum + 1e-8f));
        atomicAdd(out_loss, -term * (1.0f / 512.0f));
    }
}

// ---------- launch ----------
extern "C" void kernel_launch(void* const* d_in, const int* in_sizes, int n_in,
                              void* d_out, int out_size, void* d_ws, size_t ws_size,
                              hipStream_t stream) {
    const float* vis = (const float*)d_in[0];
    const float* tf  = (const float*)d_in[1];
    const float* ipw = (const float*)d_in[2];
    const float* ipb = (const float*)d_in[3];
    const float* opw = (const float*)d_in[4];
    const float* opb = (const float*)d_in[5];
    const float* tm  = (const float*)d_in[6];
    const float* tpl = (const float*)d_in[7];
    const float* tnl = (const float*)d_in[8];

    float* out       = (float*)d_out;
    float* out_loss  = out;
    float* out_corr  = out + 1;                  // (512,512)
    float* out_cs    = out + 1 + 512 * 512;      // (512,3)

    char* p = (char*)d_ws;
    auto alloc = [&](size_t bytes) { char* r = p; p += (bytes + 255) & ~(size_t)255; return r; };
    float* vis_n  = (float*)alloc(512 * 512 * 4);
    u16*   vis_nb = (u16*)  alloc(512 * 512 * 2);
    u16*   vis_b  = (u16*)  alloc(512 * 512 * 2);
    u16*   wqb    = (u16*)  alloc(512 * 512 * 2);
    u16*   wvb    = (u16*)  alloc(512 * 512 * 2);
    u16*   wob    = (u16*)  alloc(512 * 512 * 2);
    float* qws    = (float*)alloc(512 * 512 * 4);
    float* qk_all = (float*)alloc((size_t)512 * 8 * 512 * 4);
    float* scores = (float*)alloc((size_t)512 * 96 * 8 * 4);
    float* sims_g = (float*)alloc(512 * 96 * 4);
    u16*   u_allb = (u16*)  alloc((size_t)512 * 8 * 512 * 2);
    u16*   ctxb   = (u16*)  alloc(512 * 512 * 2);
    u16*   negsb  = (u16*)  alloc(1024 * 512 * 2);
    float* ns     = (float*)alloc(512 * 1024 * 4);
    float* pos    = (float*)alloc(512 * 4);

    const float* wk = ipw + 512 * 512;           // fp32 rows 512..1023
    const float* bv = ipb + 2 * 512;

    prep<<<896, 256, 0, stream>>>(vis, ipw, opw, vis_n, vis_nb, vis_b, wqb, wvb, wob, out_loss);
    gemm64<<<dim3(8, 8), 256, 0, stream>>>(vis_b, 512, wqb, ipb, qws, 512);        // q
    qk_proj<<<dim3(64, 8, 2), 256, 0, stream>>>(qws, wk, qk_all);
    score_pass<<<1024, 256, 0, stream>>>(tf, vis_n, qk_all, scores, sims_g);
    pv_cluster<<<512, 256, 0, stream>>>(tf, scores, sims_g, u_allb, out_cs);
    gemm_head<<<dim3(8, 8), 256, 0, stream>>>(u_allb, wvb, bv, ctxb);              // ctx (bf16)
    gemm64<<<dim3(8, 8), 256, 0, stream>>>(ctxb, 512, wob, opb, out_corr, 512);    // corrected
    negs_build<<<256, 256, 0, stream>>>(out_corr, tm, vis_n, negsb, pos);
    gemm64<<<dim3(8, 16), 256, 0, stream>>>(vis_nb, 512, negsb, nullptr, ns, 1024);
    topk_loss<<<512, 256, 0, stream>>>(ns, pos, tpl, tnl, out_loss);
}

// Round 8
// 251.827 us; speedup vs baseline: 1.0306x; 1.0306x over previous
//
#include <hip/hip_runtime.h>
#include <math.h>

typedef unsigned short u16;
typedef unsigned int u32;
typedef __attribute__((ext_vector_type(8))) short short8;   // 8 bf16 (4 VGPRs) MFMA A/B frag
typedef __attribute__((ext_vector_type(4))) float f32x4;    // MFMA C/D frag

#define EPS 1e-8f

// ---------- helpers ----------
__device__ inline float bf2f(u16 u) {
    union { u32 i; float f; } v; v.i = ((u32)u) << 16; return v.f;
}
__device__ inline u16 f2bf(float f) {  // RNE
    union { float f; u32 u; } v; v.f = f;
    u32 r = v.u + 0x7fffu + ((v.u >> 16) & 1u);
    return (u16)(r >> 16);
}
__device__ inline u32 pack2(float a, float b) {
    return (u32)f2bf(a) | ((u32)f2bf(b) << 16);
}
__device__ inline float wave_sum(float v) {
    for (int off = 32; off; off >>= 1) v += __shfl_xor(v, off, 64);
    return v;
}

// ---------- K1: prep = vis normalize (fp32+bf16) + raw bf16 + Wq/Wv/Wo cvt ----------
__global__ __launch_bounds__(256) void prep(const float* __restrict__ vis,
                                            const float* __restrict__ ipw,
                                            const float* __restrict__ opw,
                                            float* __restrict__ vis_n,
                                            u16* __restrict__ vis_nb,
                                            u16* __restrict__ vis_b,
                                            u16* __restrict__ wqb,
                                            u16* __restrict__ wvb,
                                            u16* __restrict__ wob,
                                            float* __restrict__ loss0)
{
    int bid = blockIdx.x;
    if (bid >= 128) {
        int i = ((bid - 128) * 256 + threadIdx.x) * 4;   // 786432 elems
        const float* src; u16* dst; int j;
        if (i < 262144)      { j = i;          src = ipw + j;          dst = wqb + j; }
        else if (i < 524288) { j = i - 262144; src = ipw + 524288 + j; dst = wvb + j; }
        else                 { j = i - 524288; src = opw + j;          dst = wob + j; }
        float4 v = *(const float4*)src;
        uint2 pk; pk.x = pack2(v.x, v.y); pk.y = pack2(v.z, v.w);
        *(uint2*)dst = pk;
        return;
    }
    if (bid == 0 && threadIdx.x == 0) loss0[0] = 0.0f;
    int wave = threadIdx.x >> 6, lane = threadIdx.x & 63;
    int b = bid * 4 + wave;                      // B = 512
    const float* row = vis + b * 512 + lane * 8;
    float4 x0 = *(const float4*)row;
    float4 x1 = *(const float4*)(row + 4);
    uint4 rk;
    rk.x = pack2(x0.x, x0.y); rk.y = pack2(x0.z, x0.w);
    rk.z = pack2(x1.x, x1.y); rk.w = pack2(x1.z, x1.w);
    *(uint4*)(vis_b + b*512 + lane*8) = rk;
    float ss = x0.x*x0.x + x0.y*x0.y + x0.z*x0.z + x0.w*x0.w
             + x1.x*x1.x + x1.y*x1.y + x1.z*x1.z + x1.w*x1.w;
    ss = wave_sum(ss);
    float inv = 1.0f / fmaxf(sqrtf(ss), EPS);
    float4 y0, y1;
    y0.x = x0.x*inv; y0.y = x0.y*inv; y0.z = x0.z*inv; y0.w = x0.w*inv;
    y1.x = x1.x*inv; y1.y = x1.y*inv; y1.z = x1.z*inv; y1.w = x1.w*inv;
    *(float4*)(vis_n + b*512 + lane*8)     = y0;
    *(float4*)(vis_n + b*512 + lane*8 + 4) = y1;
    uint4 pk;
    pk.x = pack2(y0.x, y0.y); pk.y = pack2(y0.z, y0.w);
    pk.z = pack2(y1.x, y1.y); pk.w = pack2(y1.z, y1.w);
    *(uint4*)(vis_nb + b*512 + lane*8) = pk;
}

// ---------- gemm64: C(MxN) = A(Mx512,bf16) @ B(Nx512,bf16)^T [+bias], fp32 out ----------
__global__ __launch_bounds__(256) void gemm64(const u16* __restrict__ A, int lda,
                                              const u16* __restrict__ B,
                                              const float* __restrict__ bias,
                                              float* __restrict__ Cf, int ldc)
{
    __shared__ __align__(16) u16 As[64 * 64];
    __shared__ __align__(16) u16 Bs[64 * 64];
    const int t = threadIdx.x, lane = t & 63, w = t >> 6;
    const int m0 = blockIdx.x * 64, n0 = blockIdx.y * 64;
    const int wm = (w >> 1) * 32, wn = (w & 1) * 32;
    const int l16 = lane & 15, quad = lane >> 4;
    const int srow = t >> 3, scol = (t & 7) * 8;

    f32x4 acc[2][2];
    for (int i = 0; i < 2; i++)
        for (int j = 0; j < 2; j++)
            for (int e = 0; e < 4; e++) acc[i][j][e] = 0.f;

    for (int ko = 0; ko < 512; ko += 64) {
        __syncthreads();
        #pragma unroll
        for (int i = 0; i < 2; i++) {
            int row = i * 32 + srow;
            *(uint4*)&As[row * 64 + scol] = *(const uint4*)&A[(size_t)(m0 + row) * lda + ko + scol];
            *(uint4*)&Bs[row * 64 + scol] = *(const uint4*)&B[(size_t)(n0 + row) * 512 + ko + scol];
        }
        __syncthreads();
        #pragma unroll
        for (int ks = 0; ks < 2; ks++) {
            short8 af[2], bfr[2];
            #pragma unroll
            for (int i = 0; i < 2; i++)
                af[i] = *(const short8*)&As[(wm + i * 16 + l16) * 64 + ks * 32 + quad * 8];
            #pragma unroll
            for (int j = 0; j < 2; j++)
                bfr[j] = *(const short8*)&Bs[(wn + j * 16 + l16) * 64 + ks * 32 + quad * 8];
            #pragma unroll
            for (int i = 0; i < 2; i++)
                #pragma unroll
                for (int j = 0; j < 2; j++)
                    acc[i][j] = __builtin_amdgcn_mfma_f32_16x16x32_bf16(af[i], bfr[j], acc[i][j], 0, 0, 0);
        }
    }
    for (int i = 0; i < 2; i++) {
        int row = m0 + wm + i * 16 + quad * 4;
        for (int j = 0; j < 2; j++) {
            int col = n0 + wn + j * 16 + l16;
            float bv = bias ? bias[col] : 0.f;
            for (int r = 0; r < 4; r++)
                Cf[(size_t)(row + r) * ldc + col] = acc[i][j][r] + bv;
        }
    }
}

// ---------- gemm_head: ctx_h(512x64) = u_h(512x512) @ Wv_h(64x512)^T + bv_h, bf16 out ----------
__global__ __launch_bounds__(256) void gemm_head(const u16* __restrict__ u_allb,
                                                 const u16* __restrict__ wvb,
                                                 const float* __restrict__ bv,
                                                 u16* __restrict__ ctxb)
{
    const int h = blockIdx.y;
    const u16* A = u_allb + h * 512;                 // lda 4096
    const u16* B = wvb + (size_t)h * 64 * 512;       // 64 rows, ldb 512
    __shared__ __align__(16) u16 As[64 * 64];
    __shared__ __align__(16) u16 Bs[64 * 64];
    const int t = threadIdx.x, lane = t & 63, w = t >> 6;
    const int m0 = blockIdx.x * 64;
    const int wm = (w >> 1) * 32, wn = (w & 1) * 32;
    const int l16 = lane & 15, quad = lane >> 4;
    const int srow = t >> 3, scol = (t & 7) * 8;

    f32x4 acc[2][2];
    for (int i = 0; i < 2; i++)
        for (int j = 0; j < 2; j++)
            for (int e = 0; e < 4; e++) acc[i][j][e] = 0.f;

    for (int ko = 0; ko < 512; ko += 64) {
        __syncthreads();
        #pragma unroll
        for (int i = 0; i < 2; i++) {
            int row = i * 32 + srow;
            *(uint4*)&As[row * 64 + scol] = *(const uint4*)&A[(size_t)(m0 + row) * 4096 + ko + scol];
            *(uint4*)&Bs[row * 64 + scol] = *(const uint4*)&B[(size_t)row * 512 + ko + scol];
        }
        __syncthreads();
        #pragma unroll
        for (int ks = 0; ks < 2; ks++) {
            short8 af[2], bfr[2];
            #pragma unroll
            for (int i = 0; i < 2; i++)
                af[i] = *(const short8*)&As[(wm + i * 16 + l16) * 64 + ks * 32 + quad * 8];
            #pragma unroll
            for (int j = 0; j < 2; j++)
                bfr[j] = *(const short8*)&Bs[(wn + j * 16 + l16) * 64 + ks * 32 + quad * 8];
            #pragma unroll
            for (int i = 0; i < 2; i++)
                #pragma unroll
                for (int j = 0; j < 2; j++)
                    acc[i][j] = __builtin_amdgcn_mfma_f32_16x16x32_bf16(af[i], bfr[j], acc[i][j], 0, 0, 0);
        }
    }
    for (int i = 0; i < 2; i++) {
        int row = m0 + wm + i * 16 + quad * 4;
        for (int j = 0; j < 2; j++) {
            int col = wn + j * 16 + l16;
            float bb = bv[h * 64 + col];
            for (int r = 0; r < 4; r++)
                ctxb[(size_t)(row + r) * 512 + h * 64 + col] = f2bf(acc[i][j][r] + bb);
        }
    }
}

// ---------- qk_proj: qk_all[b,h,j] = sum_d q[b,h*64+d] * wk[h*64+d, j]  (fp32) ----------
__global__ __launch_bounds__(256) void qk_proj(const float* __restrict__ q,
                                               const float* __restrict__ wk,
                                               float* __restrict__ qk_all)
{
    int bg = blockIdx.x, h = blockIdx.y;
    int t = threadIdx.x;
    int j = blockIdx.z * 256 + t;
    __shared__ float q8[8][64];
    {
        int r = t >> 5;
        int d0 = (t & 31) * 2;
        const float* qp = q + (bg * 8 + r) * 512 + h * 64 + d0;
        q8[r][d0] = qp[0]; q8[r][d0 + 1] = qp[1];
    }
    __syncthreads();
    float acc[8] = {0, 0, 0, 0, 0, 0, 0, 0};
    const float* wrow = wk + (size_t)(h * 64) * 512 + j;
    #pragma unroll 4
    for (int d = 0; d < 64; d++) {
        float ww = wrow[(size_t)d * 512];
        #pragma unroll
        for (int r = 0; r < 8; r++) acc[r] += q8[r][d] * ww;
    }
    #pragma unroll
    for (int r = 0; r < 8; r++)
        qk_all[((size_t)(bg * 8 + r) * 8 + h) * 512 + j] = acc[r];
}

// ---------- fused_attn: sims+cluster+attention, 1024 threads, 1 block/b ----------
// Staging is batched: no cross-lane ops inside the load loop; 12 concurrent
// shuffle trees afterwards (6 DS steps total instead of 36).
__global__ __launch_bounds__(1024) void fused_attn(const float* __restrict__ tf,
                                                   const float* __restrict__ vis_n,
                                                   const float* __restrict__ qk_all,
                                                   u16* __restrict__ u_allb,
                                                   float* __restrict__ out_cs)
{
    __shared__ __align__(16) u16 Xs[96 * 520];
    __shared__ __align__(16) u16 Qs[16 * 520];
    __shared__ __align__(16) u16 Ps[16 * 104];
    __shared__ float Sc[16 * 100];
    __shared__ float sm_[96], srt[96], linv[8];

    const int b = blockIdx.x;
    const int t = threadIdx.x, w = t >> 6, lane = t & 63;
    const int l16 = lane & 15, quad = lane >> 4;

    const float4* v4 = (const float4*)(vis_n + b * 512 + lane * 8);
    float4 va = v4[0], vb = v4[1];

    if (w < 8) {
        const float4* q4 = (const float4*)(qk_all + ((size_t)b * 8 + w) * 512 + lane * 8);
        float4 a = q4[0], c = q4[1];
        uint4 pk;
        pk.x = pack2(a.x, a.y); pk.y = pack2(a.z, a.w);
        pk.z = pack2(c.x, c.y); pk.w = pack2(c.z, c.w);
        *(uint4*)&Qs[w * 520 + lane * 8] = pk;
    }

    // ---- batched staging: 6 rows/wave, loads+FMA+pack+store only ----
    float ss[6], dt[6];
    #pragma unroll
    for (int i = 0; i < 6; i++) {
        int m = w + i * 16;
        const float4* x4 = (const float4*)(tf + ((size_t)b * 96 + m) * 512 + lane * 8);
        float4 a = x4[0], c = x4[1];
        ss[i] = a.x*a.x + a.y*a.y + a.z*a.z + a.w*a.w
              + c.x*c.x + c.y*c.y + c.z*c.z + c.w*c.w;
        dt[i] = a.x*va.x + a.y*va.y + a.z*va.z + a.w*va.w
              + c.x*vb.x + c.y*vb.y + c.z*vb.z + c.w*vb.w;
        uint4 pk;
        pk.x = pack2(a.x, a.y); pk.y = pack2(a.z, a.w);
        pk.z = pack2(c.x, c.y); pk.w = pack2(c.z, c.w);
        *(uint4*)&Xs[m * 520 + lane * 8] = pk;
    }
    // 12 concurrent shuffle trees, 6 serial steps
    #pragma unroll
    for (int off = 32; off; off >>= 1) {
        #pragma unroll
        for (int i = 0; i < 6; i++) {
            ss[i] += __shfl_xor(ss[i], off, 64);
            dt[i] += __shfl_xor(dt[i], off, 64);
        }
    }
    if (lane == 0) {
        #pragma unroll
        for (int i = 0; i < 6; i++)
            sm_[w + i * 16] = dt[i] / fmaxf(sqrtf(ss[i]), EPS);
    }
    __syncthreads();

    // scores: Sc[h=l16][m] = (X @ qk^T)/8 ; waves 0..5 take the 6 m-tiles
    if (w < 6) {
        f32x4 acc;
        for (int e = 0; e < 4; e++) acc[e] = 0.f;
        #pragma unroll
        for (int ks = 0; ks < 16; ks++) {
            short8 a = *(const short8*)&Xs[(w * 16 + l16) * 520 + ks * 32 + quad * 8];
            short8 q = *(const short8*)&Qs[l16 * 520 + ks * 32 + quad * 8];
            acc = __builtin_amdgcn_mfma_f32_16x16x32_bf16(a, q, acc, 0, 0, 0);
        }
        #pragma unroll
        for (int r = 0; r < 4; r++)
            Sc[l16 * 100 + w * 16 + quad * 4 + r] = acc[r] * 0.125f;
    }
    __syncthreads();

    if (w < 8) {
        float e0 = __expf(Sc[w * 100 + lane]);
        float e1 = (lane < 32) ? __expf(Sc[w * 100 + 64 + lane]) : 0.f;
        float l = wave_sum(e0 + e1);
        Ps[w * 104 + lane] = f2bf(e0);
        if (lane < 32) Ps[w * 104 + 64 + lane] = f2bf(e1);
        if (lane == 0) linv[w] = 1.0f / l;
    }
    if (t < 96) {
        float v = sm_[t]; int r = 0;
        for (int j = 0; j < 96; j++) {
            float u = sm_[j];
            r += (u > v) || (u == v && j < t);
        }
        srt[r] = v;
    }
    __syncthreads();

    #pragma unroll
    for (int jj = 0; jj < 2; jj++) {
        int n0 = (w * 2 + jj) * 16;
        f32x4 acc;
        for (int e = 0; e < 4; e++) acc[e] = 0.f;
        #pragma unroll
        for (int ks = 0; ks < 3; ks++) {
            short8 ap = *(const short8*)&Ps[l16 * 104 + ks * 32 + quad * 8];
            short8 bx;
            #pragma unroll
            for (int j = 0; j < 8; j++)
                bx[j] = (short)Xs[(ks * 32 + quad * 8 + j) * 520 + n0 + l16];
            acc = __builtin_amdgcn_mfma_f32_16x16x32_bf16(ap, bx, acc, 0, 0, 0);
        }
        if (quad < 2) {
            #pragma unroll
            for (int r = 0; r < 4; r++) {
                int h = quad * 4 + r;
                u_allb[((size_t)b * 8 + h) * 512 + n0 + l16] = f2bf(acc[r] * linv[h]);
            }
        }
    }
    if (t < 3) {
        float mean = 0.f;
        #pragma unroll 8
        for (int i = 0; i < 32; i++) mean += srt[t * 32 + i];
        mean *= (1.0f / 32.0f);
        float var = 0.f;
        #pragma unroll 8
        for (int i = 0; i < 32; i++) { float d = srt[t * 32 + i] - mean; var += d * d; }
        var *= (1.0f / 31.0f);
        out_cs[b * 3 + t] = mean / (sqrtf(var) + 1e-6f);
    }
}

// ---------- negs_build: normalized negatives (bf16) + pos_sim ----------
__global__ __launch_bounds__(256) void negs_build(const float* __restrict__ corrected,
                                                  const float* __restrict__ tm,
                                                  const float* __restrict__ vis_n,
                                                  u16* __restrict__ negs_nb,
                                                  float* __restrict__ pos)
{
    int wave = threadIdx.x >> 6, lane = threadIdx.x & 63;
    int j = blockIdx.x * 4 + wave;
    const float* src = (j < 512) ? (corrected + j * 512) : (tm + j * 512);
    const float* row = src + lane * 8;
    float4 x0 = *(const float4*)row;
    float4 x1 = *(const float4*)(row + 4);
    float ss = x0.x*x0.x + x0.y*x0.y + x0.z*x0.z + x0.w*x0.w
             + x1.x*x1.x + x1.y*x1.y + x1.z*x1.z + x1.w*x1.w;
    float dt = 0.f;
    if (j < 512) {
        const float* vn = vis_n + j * 512 + lane * 8;
        float4 v0 = *(const float4*)vn;
        float4 v1 = *(const float4*)(vn + 4);
        dt = x0.x*v0.x + x0.y*v0.y + x0.z*v0.z + x0.w*v0.w
           + x1.x*v1.x + x1.y*v1.y + x1.z*v1.z + x1.w*v1.w;
    }
    ss = wave_sum(ss);
    dt = wave_sum(dt);
    float inv = 1.0f / fmaxf(sqrtf(ss), EPS);
    uint4 pk;
    pk.x = pack2(x0.x*inv, x0.y*inv); pk.y = pack2(x0.z*inv, x0.w*inv);
    pk.z = pack2(x1.x*inv, x1.y*inv); pk.w = pack2(x1.z*inv, x1.w*inv);
    *(uint4*)(negs_nb + (size_t)j * 512 + lane * 8) = pk;
    if (j < 512 && lane == 0) pos[j] = dt * inv;
}

// ---------- topk_loss: top-5 (1024 distinct, first 512 mult 2) + loss ----------
__global__ __launch_bounds__(256) void topk_loss(const float* __restrict__ ns,
                                                 const float* __restrict__ pos,
                                                 const float* __restrict__ tau_p_log,
                                                 const float* __restrict__ tau_n_log,
                                                 float* __restrict__ out_loss)
{
    int b = blockIdx.x, t = threadIdx.x;
    int w = t >> 6, lane = t & 63;
    __shared__ float cand_v[4];
    __shared__ int   cand_m[4];

    const float4 raw = *(const float4*)(ns + b * 1024 + t * 4);
    float lv[4] = {raw.x, raw.y, raw.z, raw.w};
    #pragma unroll
    for (int i = 1; i < 4; i++) {
        float key = lv[i];
        int j = i - 1;
        #pragma unroll
        for (int k = 0; k < 3; k++) {
            if (j >= 0 && lv[j] < key) { lv[j + 1] = lv[j]; j--; }
        }
        lv[j + 1] = key;
    }
    int lp = 0;

    float tn = expf(tau_n_log[0]);
    float inv_tn = 1.0f / tn;
    float nsum = 0.f;
    int collected = 0;

    for (int round = 0; round < 5 && collected < 5; round++) {
        float head = (lp < 4) ? lv[lp] : -1e30f;
        float mv = head; int ml = lane;
        #pragma unroll
        for (int off = 32; off; off >>= 1) {
            float ov = __shfl_xor(mv, off, 64);
            int   ol = __shfl_xor(ml, off, 64);
            if (ov > mv || (ov == mv && ol < ml)) { mv = ov; ml = ol; }
        }
        if (lane == 0) { cand_v[w] = mv; cand_m[w] = ml; }
        __syncthreads();
        float bv = cand_v[0]; int bw = 0;
        #pragma unroll
        for (int i = 1; i < 4; i++) {
            if (cand_v[i] > bv) { bv = cand_v[i]; bw = i; }
        }
        int bl = cand_m[bw];
        __syncthreads();
        if (w == bw && lane == bl) lp++;
        int wm = ((bw * 64 + bl) < 128) ? 2 : 1;
        int take = (wm < (5 - collected)) ? wm : (5 - collected);
        nsum += (float)take * __expf(bv * inv_tn);
        collected += take;
    }

    if (t == 0) {
        float tp = expf(tau_p_log[0]);
        float p = expf(pos[b] / tp);
        float term = logf(p / (p + nsum + 1e-8f));
        atomicAdd(out_loss, -term * (1.0f / 512.0f));
    }
}

// ---------- launch ----------
extern "C" void kernel_launch(void* const* d_in, const int* in_sizes, int n_in,
                              void* d_out, int out_size, void* d_ws, size_t ws_size,
                              hipStream_t stream) {
    const float* vis = (const float*)d_in[0];
    const float* tf  = (const float*)d_in[1];
    const float* ipw = (const float*)d_in[2];
    const float* ipb = (const float*)d_in[3];
    const float* opw = (const float*)d_in[4];
    const float* opb = (const float*)d_in[5];
    const float* tm  = (const float*)d_in[6];
    const float* tpl = (const float*)d_in[7];
    const float* tnl = (const float*)d_in[8];

    float* out       = (float*)d_out;
    float* out_loss  = out;
    float* out_corr  = out + 1;                  // (512,512)
    float* out_cs    = out + 1 + 512 * 512;      // (512,3)

    char* p = (char*)d_ws;
    auto alloc = [&](size_t bytes) { char* r = p; p += (bytes + 255) & ~(size_t)255; return r; };
    float* vis_n  = (float*)alloc(512 * 512 * 4);
    u16*   vis_nb = (u16*)  alloc(512 * 512 * 2);
    u16*   vis_b  = (u16*)  alloc(512 * 512 * 2);
    u16*   wqb    = (u16*)  alloc(512 * 512 * 2);
    u16*   wvb    = (u16*)  alloc(512 * 512 * 2);
    u16*   wob    = (u16*)  alloc(512 * 512 * 2);
    float* qws    = (float*)alloc(512 * 512 * 4);
    float* qk_all = (float*)alloc((size_t)512 * 8 * 512 * 4);
    u16*   u_allb = (u16*)  alloc((size_t)512 * 8 * 512 * 2);
    u16*   ctxb   = (u16*)  alloc(512 * 512 * 2);
    u16*   negsb  = (u16*)  alloc(1024 * 512 * 2);
    float* ns     = (float*)alloc(512 * 1024 * 4);
    float* pos    = (float*)alloc(512 * 4);

    const float* wk = ipw + 512 * 512;           // fp32 rows 512..1023
    const float* bv = ipb + 2 * 512;

    prep<<<896, 256, 0, stream>>>(vis, ipw, opw, vis_n, vis_nb, vis_b, wqb, wvb, wob, out_loss);
    gemm64<<<dim3(8, 8), 256, 0, stream>>>(vis_b, 512, wqb, ipb, qws, 512);        // q
    qk_proj<<<dim3(64, 8, 2), 256, 0, stream>>>(qws, wk, qk_all);
    fused_attn<<<512, 1024, 0, stream>>>(tf, vis_n, qk_all, u_allb, out_cs);
    gemm_head<<<dim3(8, 8), 256, 0, stream>>>(u_allb, wvb, bv, ctxb);              // ctx (bf16)
    gemm64<<<dim3(8, 8), 256, 0, stream>>>(ctxb, 512, wob, opb, out_corr, 512);    // corrected
    negs_build<<<256, 256, 0, stream>>>(out_corr, tm, vis_n, negsb, pos);
    gemm64<<<dim3(8, 16), 256, 0, stream>>>(vis_nb, 512, negsb, nullptr, ns, 1024);
    topk_loss<<<512, 256, 0, stream>>>(ns, pos, tpl, tnl, out_loss);
}